// Round 1
// baseline (1535.066 us; speedup 1.0000x reference)
//
#include <hip/hip_runtime.h>

// Luenberger state estimator: T=2048 sequential steps, B=1024 independent
// batch elements. Mapping: 1 wave per element (1024 blocks x 64 threads),
// lane h = hidden unit h of BOTH MLPs. Weights in per-lane VGPRs, state x[8]
// replicated per lane, DPP wave reduction for the 8 output sums per step.

#define T_STEPS 2048
#define B_SZ    1024
#define NX      8
#define NU      2
#define NY      2
#define HID     64

__device__ __forceinline__ float tanh_fast(float z) {
  // tanh(z) = 1 - 2/(exp(2z)+1). Handles +-inf saturation correctly:
  // exp(+inf)=inf -> 1-0 = 1 ; exp(-inf)=0 -> 1-2 = -1.
  float e2 = __expf(2.0f * z);
  return 1.0f - 2.0f / (e2 + 1.0f);
}

template <int CTRL, int RMASK>
__device__ __forceinline__ float dpp_add(float acc) {
  // acc + dpp_move(acc); masked/invalid lanes contribute old=0.
  int moved = __builtin_amdgcn_update_dpp(0, __float_as_int(acc), CTRL, RMASK, 0xf, true);
  return acc + __int_as_float(moved);
}

__global__ __launch_bounds__(64, 1) void luen_kernel(
    const float* __restrict__ u, const float* __restrict__ y,
    const float* __restrict__ Wf1, const float* __restrict__ bf1,
    const float* __restrict__ Wf2, const float* __restrict__ bf2,
    const float* __restrict__ Wg, const float* __restrict__ bg,
    const float* __restrict__ Wk1, const float* __restrict__ bk1,
    const float* __restrict__ Wk2, const float* __restrict__ bk2,
    float* __restrict__ out) {
  const int eb = blockIdx.x;   // batch element
  const int h  = threadIdx.x;  // hidden unit (0..63)

  // ---- per-lane weight columns (lane h owns hidden unit h of both nets) ----
  float wf1[NX + NU];
#pragma unroll
  for (int k = 0; k < NX + NU; ++k) wf1[k] = Wf1[k * HID + h];  // (10,64)
  float wk1[NX];
#pragma unroll
  for (int k = 0; k < NX; ++k) wk1[k] = Wk1[k * HID + h];       // (8,64)
  float wf2[NX];
#pragma unroll
  for (int j = 0; j < NX; ++j) wf2[j] = Wf2[h * NX + j];        // (64,8)
  float wk2[NX * NY];
#pragma unroll
  for (int j = 0; j < NX * NY; ++j) wk2[j] = Wk2[h * (NX * NY) + j];  // (64,16)
  const float bf1h = bf1[h];
  const float bk1h = bk1[h];

  // ---- uniform (replicated) small tensors ----
  float wg[NX * NY];
#pragma unroll
  for (int j = 0; j < NX * NY; ++j) wg[j] = Wg[j];              // (8,2)
  const float bg0 = bg[0], bg1 = bg[1];
  float bf2v[NX];
#pragma unroll
  for (int k = 0; k < NX; ++k) bf2v[k] = bf2[k];
  float bk2v[NX * NY];
#pragma unroll
  for (int j = 0; j < NX * NY; ++j) bk2v[j] = bk2[j];

  const float* __restrict__ ue = u + (size_t)eb * NU;
  const float* __restrict__ ye = y + (size_t)eb * NY;

  float x[NX];
#pragma unroll
  for (int k = 0; k < NX; ++k) x[k] = 0.0f;

  // prefetch t=0
  float cu0 = ue[0], cu1 = ue[1];
  float cy0 = ye[0], cy1 = ye[1];

  for (int t = 0; t < T_STEPS; ++t) {
    // prefetch next step's u/y (clamped; hides global latency under compute)
    const int tn = (t + 1 < T_STEPS) ? (t + 1) : (T_STEPS - 1);
    const float nu0 = ue[(size_t)tn * (B_SZ * NU) + 0];
    const float nu1 = ue[(size_t)tn * (B_SZ * NU) + 1];
    const float ny0 = ye[(size_t)tn * (B_SZ * NY) + 0];
    const float ny1 = ye[(size_t)tn * (B_SZ * NY) + 1];

    // y_hat = x@Wg + bg ; e = y_hat - y_t   (replicated per lane; needs x only)
    float yh0 = bg0, yh1 = bg1;
#pragma unroll
    for (int k = 0; k < NX; ++k) {
      yh0 = fmaf(x[k], wg[2 * k + 0], yh0);
      yh1 = fmaf(x[k], wg[2 * k + 1], yh1);
    }
    const float e0 = yh0 - cy0;
    const float e1 = yh1 - cy1;

    // f-net hidden unit h:  pre = [x;u] . Wf1[:,h] + bf1[h]   (2 chains for ILP)
    float pa = fmaf(x[0], wf1[0], fmaf(x[1], wf1[1], fmaf(x[2], wf1[2], fmaf(x[3], wf1[3], bf1h))));
    float pb = fmaf(x[4], wf1[4], fmaf(x[5], wf1[5], fmaf(x[6], wf1[6],
               fmaf(x[7], wf1[7], fmaf(cu0, wf1[8], cu1 * wf1[9])))));
    const float h1 = tanh_fast(pa + pb);

    // k-net hidden unit h
    float qa = fmaf(x[0], wk1[0], fmaf(x[1], wk1[1], fmaf(x[2], wk1[2], fmaf(x[3], wk1[3], bk1h))));
    float qb = fmaf(x[4], wk1[4], fmaf(x[5], wk1[5], fmaf(x[6], wk1[6], x[7] * wk1[7])));
    const float h2 = tanh_fast(qa + qb);

    // Per-lane contribution to x update (folds dx AND K@e into ONE reduction):
    // c[k] = h1*Wf2[h][k] + h2*(Wk2[h][2k]*e0 + Wk2[h][2k+1]*e1)
    float c[NX];
#pragma unroll
    for (int k = 0; k < NX; ++k) {
      const float ke = fmaf(wk2[2 * k + 1], e1, wk2[2 * k] * e0);
      c[k] = fmaf(h1, wf2[k], h2 * ke);
    }

    // Wave-wide sum of the 8 c[k] values: canonical DPP reduce -> lane 63.
    // row_shr 1/2/4/8 (within-16 prefix), bcast15 (rows 1,3), bcast31 (rows 2,3).
#pragma unroll
    for (int k = 0; k < NX; ++k) c[k] = dpp_add<0x111, 0xf>(c[k]);
#pragma unroll
    for (int k = 0; k < NX; ++k) c[k] = dpp_add<0x112, 0xf>(c[k]);
#pragma unroll
    for (int k = 0; k < NX; ++k) c[k] = dpp_add<0x114, 0xf>(c[k]);
#pragma unroll
    for (int k = 0; k < NX; ++k) c[k] = dpp_add<0x118, 0xf>(c[k]);
#pragma unroll
    for (int k = 0; k < NX; ++k) c[k] = dpp_add<0x142, 0xa>(c[k]);
#pragma unroll
    for (int k = 0; k < NX; ++k) c[k] = dpp_add<0x143, 0xc>(c[k]);

    // x_new[k] = x[k] + bf2[k] + (bk2[2k]*e0 + bk2[2k+1]*e1) + sum_h c_h[k]
#pragma unroll
    for (int k = 0; k < NX; ++k) {
      const float s = __int_as_float(__builtin_amdgcn_readlane(__float_as_int(c[k]), 63));
      const float bias = bf2v[k] + fmaf(bk2v[2 * k], e0, bk2v[2 * k + 1] * e1);
      x[k] = x[k] + bias + s;  // s is an SGPR operand
    }

    cu0 = nu0; cu1 = nu1; cy0 = ny0; cy1 = ny1;
  }

  if (h == 0) {
#pragma unroll
    for (int k = 0; k < NX; ++k) out[eb * NX + k] = x[k];
  }
}

extern "C" void kernel_launch(void* const* d_in, const int* in_sizes, int n_in,
                              void* d_out, int out_size, void* d_ws, size_t ws_size,
                              hipStream_t stream) {
  const float* u   = (const float*)d_in[0];
  const float* y   = (const float*)d_in[1];
  const float* Wf1 = (const float*)d_in[2];
  const float* bf1 = (const float*)d_in[3];
  const float* Wf2 = (const float*)d_in[4];
  const float* bf2 = (const float*)d_in[5];
  const float* Wg  = (const float*)d_in[6];
  const float* bg  = (const float*)d_in[7];
  const float* Wk1 = (const float*)d_in[8];
  const float* bk1 = (const float*)d_in[9];
  const float* Wk2 = (const float*)d_in[10];
  const float* bk2 = (const float*)d_in[11];

  luen_kernel<<<dim3(B_SZ), dim3(HID), 0, stream>>>(
      u, y, Wf1, bf1, Wf2, bf2, Wg, bg, Wk1, bk1, Wk2, bk2, (float*)d_out);
}

// Round 2
// 953.692 us; speedup vs baseline: 1.6096x; 1.6096x over previous
//
#include <hip/hip_runtime.h>

// Luenberger state estimator: T=2048 sequential steps, B=1024 independent
// batch elements. 1 wave per element (1024 blocks x 64 threads), lane h =
// hidden unit h of BOTH MLPs. R2 changes vs R1:
//  - unroll-by-4 ring prefetch of u/y (depth 3..6) to hide global latency
//  - v_pk_fma_f32 packed fp32 for y_hat / pre-dots / c (2 FMA per instr)
//  - biases bf2,bk2 folded (scaled 1/64) into per-lane c contributions
//  - tanh via exp2 with weights pre-scaled by 2*log2(e)  (4 instr/tanh)
// DPP reduction kept verbatim from R1 (proven correct).

#define T_STEPS 2048
#define B_SZ    1024
#define NX      8
#define NU      2
#define NY      2
#define HID     64

typedef float v2f __attribute__((ext_vector_type(2)));

__device__ __forceinline__ v2f pk_fma(v2f a, v2f b, v2f c) {
  v2f d;
  asm("v_pk_fma_f32 %0, %1, %2, %3" : "=v"(d) : "v"(a), "v"(b), "v"(c));
  return d;
}

__device__ __forceinline__ float tanh_pre(float p) {
  // input pre-scaled by 2*log2(e): tanh(z) = 1 - 2/(2^p + 1), p = 2z*log2e
  float e2 = __builtin_amdgcn_exp2f(p);
  float r  = __builtin_amdgcn_rcpf(e2 + 1.0f);
  return fmaf(-2.0f, r, 1.0f);
}

template <int CTRL, int RMASK>
__device__ __forceinline__ float dpp_add(float acc) {
  int moved = __builtin_amdgcn_update_dpp(0, __float_as_int(acc), CTRL, RMASK, 0xf, true);
  return acc + __int_as_float(moved);
}

__device__ __forceinline__ float wave_reduce_to63(float c) {
  c = dpp_add<0x111, 0xf>(c);  // row_shr:1
  c = dpp_add<0x112, 0xf>(c);  // row_shr:2
  c = dpp_add<0x114, 0xf>(c);  // row_shr:4
  c = dpp_add<0x118, 0xf>(c);  // row_shr:8
  c = dpp_add<0x142, 0xa>(c);  // row_bcast:15
  c = dpp_add<0x143, 0xc>(c);  // row_bcast:31
  return c;
}

__global__ __launch_bounds__(64, 1) void luen_kernel(
    const float* __restrict__ u, const float* __restrict__ y,
    const float* __restrict__ Wf1, const float* __restrict__ bf1,
    const float* __restrict__ Wf2, const float* __restrict__ bf2,
    const float* __restrict__ Wg, const float* __restrict__ bg,
    const float* __restrict__ Wk1, const float* __restrict__ bk1,
    const float* __restrict__ Wk2, const float* __restrict__ bk2,
    float* __restrict__ out) {
  const int eb = blockIdx.x;   // batch element
  const int h  = threadIdx.x;  // hidden unit (0..63)

  const float TS = 2.885390081777927f;  // 2*log2(e) tanh pre-scale
  const float INV64 = 1.0f / 64.0f;

  // ---- per-lane weight columns, packed into fp32 pairs ----
  v2f wf1p[5];                            // Wf1 (10,64) column h, scaled
#pragma unroll
  for (int p = 0; p < 5; ++p)
    wf1p[p] = v2f{TS * Wf1[(2 * p) * HID + h], TS * Wf1[(2 * p + 1) * HID + h]};
  v2f wk1p[4];                            // Wk1 (8,64) column h, scaled
#pragma unroll
  for (int p = 0; p < 4; ++p)
    wk1p[p] = v2f{TS * Wk1[(2 * p) * HID + h], TS * Wk1[(2 * p + 1) * HID + h]};
  const float bf1h = TS * bf1[h];
  const float bk1h = TS * bk1[h];

  v2f wf2p[4], bf2sp[4];                  // Wf2 (64,8) row h; bf2/64 shares
#pragma unroll
  for (int p = 0; p < 4; ++p) {
    wf2p[p]  = v2f{Wf2[h * NX + 2 * p], Wf2[h * NX + 2 * p + 1]};
    bf2sp[p] = v2f{INV64 * bf2[2 * p], INV64 * bf2[2 * p + 1]};
  }
  // Wk2 (64,16) row h: split into e0-coeffs (even cols) / e1-coeffs (odd),
  // paired over k: pair p covers k=2p,2p+1 -> cols {4p,4p+2} / {4p+1,4p+3}
  v2f wk2e[4], wk2o[4], bk2se[4], bk2so[4];
#pragma unroll
  for (int p = 0; p < 4; ++p) {
    const float* r = Wk2 + h * (NX * NY);
    wk2e[p]  = v2f{r[4 * p], r[4 * p + 2]};
    wk2o[p]  = v2f{r[4 * p + 1], r[4 * p + 3]};
    bk2se[p] = v2f{INV64 * bk2[4 * p], INV64 * bk2[4 * p + 2]};
    bk2so[p] = v2f{INV64 * bk2[4 * p + 1], INV64 * bk2[4 * p + 3]};
  }
  // Wg (8,2) columns, paired over k (uniform, replicated per lane)
  v2f wgc0[4], wgc1[4];
#pragma unroll
  for (int p = 0; p < 4; ++p) {
    wgc0[p] = v2f{Wg[4 * p], Wg[4 * p + 2]};
    wgc1[p] = v2f{Wg[4 * p + 1], Wg[4 * p + 3]};
  }
  const float bg0 = bg[0], bg1 = bg[1];

  const v2f* __restrict__ pu = reinterpret_cast<const v2f*>(u + (size_t)eb * NU);
  const v2f* __restrict__ py = reinterpret_cast<const v2f*>(y + (size_t)eb * NY);
  // per-t stride in v2f units: B*2 floats / 2
  const int STR = B_SZ;  // 1024 v2f

  v2f x2[4];
#pragma unroll
  for (int p = 0; p < 4; ++p) x2[p] = v2f{0.0f, 0.0f};

  // ring prefetch: slots 0..2 hold t=0..2
  v2f bu[4], by[4];
  bu[0] = pu[0 * STR]; by[0] = py[0 * STR];
  bu[1] = pu[1 * STR]; by[1] = py[1 * STR];
  bu[2] = pu[2 * STR]; by[2] = py[2 * STR];
  bu[3] = v2f{0, 0};   by[3] = v2f{0, 0};

#define STEP(T_, S_)                                                          \
  {                                                                           \
    /* prefetch t+3 into slot (S_+3)&3 (clamped at tail) */                   \
    int tn = (T_) + 3; if (tn > T_STEPS - 1) tn = T_STEPS - 1;                \
    bu[((S_) + 3) & 3] = pu[(size_t)tn * STR];                                \
    by[((S_) + 3) & 3] = py[(size_t)tn * STR];                                \
    const v2f cu = bu[S_];                                                    \
    const v2f cy = by[S_];                                                    \
    /* y_hat: packed over k-pairs, horizontal add at the end */               \
    v2f a0 = v2f{bg0, 0.0f}, a1 = v2f{bg1, 0.0f};                             \
    a0 = pk_fma(x2[0], wgc0[0], a0); a1 = pk_fma(x2[0], wgc1[0], a1);         \
    a0 = pk_fma(x2[1], wgc0[1], a0); a1 = pk_fma(x2[1], wgc1[1], a1);         \
    a0 = pk_fma(x2[2], wgc0[2], a0); a1 = pk_fma(x2[2], wgc1[2], a1);         \
    a0 = pk_fma(x2[3], wgc0[3], a0); a1 = pk_fma(x2[3], wgc1[3], a1);         \
    const float e0 = (a0[0] + a0[1]) - cy[0];                                 \
    const float e1 = (a1[0] + a1[1]) - cy[1];                                 \
    /* f-net pre-activation (packed dot over [x;u]) */                        \
    v2f pf2 = v2f{bf1h, 0.0f};                                                \
    pf2 = pk_fma(x2[0], wf1p[0], pf2);                                        \
    pf2 = pk_fma(x2[1], wf1p[1], pf2);                                        \
    pf2 = pk_fma(x2[2], wf1p[2], pf2);                                        \
    pf2 = pk_fma(x2[3], wf1p[3], pf2);                                        \
    pf2 = pk_fma(cu,    wf1p[4], pf2);                                        \
    const float h1 = tanh_pre(pf2[0] + pf2[1]);                               \
    /* k-net pre-activation */                                                \
    v2f pk2 = v2f{bk1h, 0.0f};                                                \
    pk2 = pk_fma(x2[0], wk1p[0], pk2);                                        \
    pk2 = pk_fma(x2[1], wk1p[1], pk2);                                        \
    pk2 = pk_fma(x2[2], wk1p[2], pk2);                                        \
    pk2 = pk_fma(x2[3], wk1p[3], pk2);                                        \
    const float h2 = tanh_pre(pk2[0] + pk2[1]);                               \
    /* per-lane contribution pairs (bias shares folded in):                   \
       c[k] = h1*wf2[k] + bf2[k]/64 + e0*(h2*wk2[2k]+bk2[2k]/64)              \
                               + e1*(h2*wk2[2k+1]+bk2[2k+1]/64) */            \
    const v2f h1s = v2f{h1, h1}, h2s = v2f{h2, h2};                           \
    const v2f e0s = v2f{e0, e0}, e1s = v2f{e1, e1};                           \
    float c[NX];                                                              \
    _Pragma("unroll")                                                         \
    for (int p = 0; p < 4; ++p) {                                             \
      v2f t0 = pk_fma(h2s, wk2e[p], bk2se[p]);                                \
      v2f t1 = pk_fma(h2s, wk2o[p], bk2so[p]);                                \
      v2f cp = pk_fma(h1s, wf2p[p], bf2sp[p]);                                \
      cp = pk_fma(t0, e0s, cp);                                               \
      cp = pk_fma(t1, e1s, cp);                                               \
      c[2 * p] = cp[0]; c[2 * p + 1] = cp[1];                                 \
    }                                                                         \
    /* wave-wide sums -> lane 63 -> SGPR broadcast */                         \
    _Pragma("unroll")                                                         \
    for (int k = 0; k < NX; ++k) c[k] = wave_reduce_to63(c[k]);               \
    _Pragma("unroll")                                                         \
    for (int p = 0; p < 4; ++p) {                                             \
      x2[p][0] += __int_as_float(__builtin_amdgcn_readlane(__float_as_int(c[2 * p]), 63));     \
      x2[p][1] += __int_as_float(__builtin_amdgcn_readlane(__float_as_int(c[2 * p + 1]), 63)); \
    }                                                                         \
  }

  for (int t = 0; t < T_STEPS; t += 4) {
    STEP(t + 0, 0);
    STEP(t + 1, 1);
    STEP(t + 2, 2);
    STEP(t + 3, 3);
  }
#undef STEP

  if (h == 0) {
#pragma unroll
    for (int p = 0; p < 4; ++p) {
      out[eb * NX + 2 * p]     = x2[p][0];
      out[eb * NX + 2 * p + 1] = x2[p][1];
    }
  }
}

extern "C" void kernel_launch(void* const* d_in, const int* in_sizes, int n_in,
                              void* d_out, int out_size, void* d_ws, size_t ws_size,
                              hipStream_t stream) {
  const float* u   = (const float*)d_in[0];
  const float* y   = (const float*)d_in[1];
  const float* Wf1 = (const float*)d_in[2];
  const float* bf1 = (const float*)d_in[3];
  const float* Wf2 = (const float*)d_in[4];
  const float* bf2 = (const float*)d_in[5];
  const float* Wg  = (const float*)d_in[6];
  const float* bg  = (const float*)d_in[7];
  const float* Wk1 = (const float*)d_in[8];
  const float* bk1 = (const float*)d_in[9];
  const float* Wk2 = (const float*)d_in[10];
  const float* bk2 = (const float*)d_in[11];

  luen_kernel<<<dim3(B_SZ), dim3(HID), 0, stream>>>(
      u, y, Wf1, bf1, Wf2, bf2, Wg, bg, Wk1, bk1, Wk2, bk2, (float*)d_out);
}

// Round 3
// 684.422 us; speedup vs baseline: 2.2429x; 1.3934x over previous
//
#include <hip/hip_runtime.h>

// Luenberger state estimator: T=2048 sequential steps, B=1024 independent
// elements. 1 wave/element (1024 blocks x 64 threads), lane h = hidden unit h
// of BOTH MLPs. R3 changes vs R2:
//  - reduction: permlane32_swap fold (8->4 regs) + 5-stage DPP half-reduce
//    (shr1/2/4/8 + bcast15), runtime direction probe + variable readlane
//  - tied-accumulator inline asm (v_pk_fma_f32 %0,%1,%2,%0) kills reg copies
//  - ping-pong A/B group prefetch (4 steps/group, depth 2 groups): no ring
//    copies, no clamp select, no per-step address mul

#define T_STEPS 2048
#define B_SZ    1024
#define NX      8
#define HID     64

typedef float v2f __attribute__((ext_vector_type(2)));

// fresh-dest packed fma: d = a*b + c (4-operand VOP3P, no copies)
__device__ __forceinline__ v2f pk_fma(v2f a, v2f b, v2f c) {
  v2f d;
  asm("v_pk_fma_f32 %0, %1, %2, %3" : "=v"(d) : "v"(a), "v"(b), "v"(c));
  return d;
}
// tied accumulator: acc = a*b + acc (in-place, no copies)
__device__ __forceinline__ void pk_fma_acc(v2f& acc, v2f a, v2f b) {
  asm("v_pk_fma_f32 %0, %1, %2, %0" : "+v"(acc) : "v"(a), "v"(b));
}

__device__ __forceinline__ float tanh_pre(float p) {
  // input pre-scaled by 2*log2(e): tanh(z) = 1 - 2/(2^p + 1)
  float e2 = __builtin_amdgcn_exp2f(p);
  float r  = __builtin_amdgcn_rcpf(e2 + 1.0f);
  return fmaf(-2.0f, r, 1.0f);
}

template <int CTRL, int RMASK>
__device__ __forceinline__ float dpp_add(float acc) {
  int moved = __builtin_amdgcn_update_dpp(0, __float_as_int(acc), CTRL, RMASK, 0xf, true);
  return acc + __int_as_float(moved);
}

// after this, lane 31 = sum(lanes 0..31), lane 63 = sum(lanes 32..63)
__device__ __forceinline__ float half_reduce(float c) {
  c = dpp_add<0x111, 0xf>(c);  // row_shr:1
  c = dpp_add<0x112, 0xf>(c);  // row_shr:2
  c = dpp_add<0x114, 0xf>(c);  // row_shr:4
  c = dpp_add<0x118, 0xf>(c);  // row_shr:8
  c = dpp_add<0x142, 0xa>(c);  // row_bcast:15 into rows 1,3
  return c;
}

__device__ __forceinline__ void swap32(float& a, float& b) {
  asm("v_permlane32_swap_b32 %0, %1" : "+v"(a), "+v"(b));
}

__global__ __launch_bounds__(64, 1) void luen_kernel(
    const float* __restrict__ u, const float* __restrict__ y,
    const float* __restrict__ Wf1, const float* __restrict__ bf1,
    const float* __restrict__ Wf2, const float* __restrict__ bf2,
    const float* __restrict__ Wg, const float* __restrict__ bg,
    const float* __restrict__ Wk1, const float* __restrict__ bk1,
    const float* __restrict__ Wk2, const float* __restrict__ bk2,
    float* __restrict__ out) {
  const int eb = blockIdx.x;
  const int h  = threadIdx.x;

  const float TS = 2.885390081777927f;  // 2*log2(e)
  const float INV64 = 1.0f / 64.0f;

  // ---- per-lane weight columns ----
  v2f wf1p[5];
#pragma unroll
  for (int p = 0; p < 5; ++p)
    wf1p[p] = v2f{TS * Wf1[(2 * p) * HID + h], TS * Wf1[(2 * p + 1) * HID + h]};
  v2f wk1p[4];
#pragma unroll
  for (int p = 0; p < 4; ++p)
    wk1p[p] = v2f{TS * Wk1[(2 * p) * HID + h], TS * Wk1[(2 * p + 1) * HID + h]};

  v2f wf2p[4], bf2sp[4];
#pragma unroll
  for (int p = 0; p < 4; ++p) {
    wf2p[p]  = v2f{Wf2[h * NX + 2 * p], Wf2[h * NX + 2 * p + 1]};
    bf2sp[p] = v2f{INV64 * bf2[2 * p], INV64 * bf2[2 * p + 1]};
  }
  v2f wk2e[4], wk2o[4], bk2se[4], bk2so[4];
#pragma unroll
  for (int p = 0; p < 4; ++p) {
    const float* r = Wk2 + h * (NX * 2);
    wk2e[p]  = v2f{r[4 * p], r[4 * p + 2]};
    wk2o[p]  = v2f{r[4 * p + 1], r[4 * p + 3]};
    bk2se[p] = v2f{INV64 * bk2[4 * p], INV64 * bk2[4 * p + 2]};
    bk2so[p] = v2f{INV64 * bk2[4 * p + 1], INV64 * bk2[4 * p + 3]};
  }
  v2f wgc0[4], wgc1[4];
#pragma unroll
  for (int p = 0; p < 4; ++p) {
    wgc0[p] = v2f{Wg[4 * p], Wg[4 * p + 2]};
    wgc1[p] = v2f{Wg[4 * p + 1], Wg[4 * p + 3]};
  }
  // chain-head constants (live in regs, consumed as src2 -> zero per-step movs)
  const v2f a0i = v2f{bg[0], 0.0f};
  const v2f a1i = v2f{bg[1], 0.0f};
  const v2f pfi = v2f{TS * bf1[h], 0.0f};
  const v2f pki = v2f{TS * bk1[h], 0.0f};

  // ---- permlane32_swap direction probe (one-time) ----
  // dir1 (D.lo<->S.hi): probe' keeps its upper half -> lane32 reads 1.
  float probe = (h < 32) ? 0.0f : 1.0f;
  float zf = 0.0f;
  swap32(probe, zf);
  const bool dir1 = __builtin_amdgcn_readlane(__float_as_int(probe), 32) != 0;
  // d_j built from swap32(c[j], c[j+4]) + add:
  //  dir1: lanes<32 hold c[j+4] pair-sums, lanes>=32 hold c[j] pair-sums
  //  => S[j] at lane 63, S[j+4] at lane 31 (reversed for dir2)
  const int laneA = dir1 ? 63 : 31;  // sum of c[j]
  const int laneB = dir1 ? 31 : 63;  // sum of c[j+4]

  const v2f* __restrict__ pu = reinterpret_cast<const v2f*>(u) + eb;
  const v2f* __restrict__ py = reinterpret_cast<const v2f*>(y) + eb;
  const int STR = B_SZ;  // per-t stride in v2f

  v2f x2[4];
#pragma unroll
  for (int p = 0; p < 4; ++p) x2[p] = v2f{0.0f, 0.0f};

  v2f Au[4], Ay[4], Bu[4], By[4];

#define LOADG(SET_u, SET_y)                          \
  {                                                  \
    SET_u[0] = pu[0 * STR]; SET_u[1] = pu[1 * STR];  \
    SET_u[2] = pu[2 * STR]; SET_u[3] = pu[3 * STR];  \
    SET_y[0] = py[0 * STR]; SET_y[1] = py[1 * STR];  \
    SET_y[2] = py[2 * STR]; SET_y[3] = py[3 * STR];  \
    pu += 4 * STR; py += 4 * STR;                    \
  }

#define STEP(CU_, CY_)                                                        \
  {                                                                           \
    const v2f cu = (CU_);                                                     \
    const v2f cy = (CY_);                                                     \
    /* y_hat and error */                                                     \
    v2f a0 = pk_fma(x2[0], wgc0[0], a0i);                                     \
    v2f a1 = pk_fma(x2[0], wgc1[0], a1i);                                     \
    pk_fma_acc(a0, x2[1], wgc0[1]); pk_fma_acc(a1, x2[1], wgc1[1]);           \
    pk_fma_acc(a0, x2[2], wgc0[2]); pk_fma_acc(a1, x2[2], wgc1[2]);           \
    pk_fma_acc(a0, x2[3], wgc0[3]); pk_fma_acc(a1, x2[3], wgc1[3]);           \
    const float e0 = a0[0] + a0[1] - cy[0];                                   \
    const float e1 = a1[0] + a1[1] - cy[1];                                   \
    /* f-net hidden unit h */                                                 \
    v2f pf = pk_fma(x2[0], wf1p[0], pfi);                                     \
    pk_fma_acc(pf, x2[1], wf1p[1]);                                           \
    pk_fma_acc(pf, x2[2], wf1p[2]);                                           \
    pk_fma_acc(pf, x2[3], wf1p[3]);                                           \
    pk_fma_acc(pf, cu, wf1p[4]);                                              \
    const float h1 = tanh_pre(pf[0] + pf[1]);                                 \
    /* k-net hidden unit h */                                                 \
    v2f pkv = pk_fma(x2[0], wk1p[0], pki);                                    \
    pk_fma_acc(pkv, x2[1], wk1p[1]);                                          \
    pk_fma_acc(pkv, x2[2], wk1p[2]);                                          \
    pk_fma_acc(pkv, x2[3], wk1p[3]);                                          \
    const float h2 = tanh_pre(pkv[0] + pkv[1]);                               \
    /* per-lane contributions (biases/64 folded in) */                        \
    const v2f h1s = {h1, h1}, h2s = {h2, h2};                                 \
    const v2f e0s = {e0, e0}, e1s = {e1, e1};                                 \
    float c0, c1, c2, c3, c4, c5, c6, c7;                                     \
    {                                                                         \
      v2f t0 = pk_fma(h2s, wk2e[0], bk2se[0]);                                \
      v2f t1 = pk_fma(h2s, wk2o[0], bk2so[0]);                                \
      v2f cp = pk_fma(h1s, wf2p[0], bf2sp[0]);                                \
      pk_fma_acc(cp, t0, e0s); pk_fma_acc(cp, t1, e1s);                       \
      c0 = cp[0]; c1 = cp[1];                                                 \
    }                                                                         \
    {                                                                         \
      v2f t0 = pk_fma(h2s, wk2e[1], bk2se[1]);                                \
      v2f t1 = pk_fma(h2s, wk2o[1], bk2so[1]);                                \
      v2f cp = pk_fma(h1s, wf2p[1], bf2sp[1]);                                \
      pk_fma_acc(cp, t0, e0s); pk_fma_acc(cp, t1, e1s);                       \
      c2 = cp[0]; c3 = cp[1];                                                 \
    }                                                                         \
    {                                                                         \
      v2f t0 = pk_fma(h2s, wk2e[2], bk2se[2]);                                \
      v2f t1 = pk_fma(h2s, wk2o[2], bk2so[2]);                                \
      v2f cp = pk_fma(h1s, wf2p[2], bf2sp[2]);                                \
      pk_fma_acc(cp, t0, e0s); pk_fma_acc(cp, t1, e1s);                       \
      c4 = cp[0]; c5 = cp[1];                                                 \
    }                                                                         \
    {                                                                         \
      v2f t0 = pk_fma(h2s, wk2e[3], bk2se[3]);                                \
      v2f t1 = pk_fma(h2s, wk2o[3], bk2so[3]);                                \
      v2f cp = pk_fma(h1s, wf2p[3], bf2sp[3]);                                \
      pk_fma_acc(cp, t0, e0s); pk_fma_acc(cp, t1, e1s);                       \
      c6 = cp[0]; c7 = cp[1];                                                 \
    }                                                                         \
    /* fold 8 -> 4 via permlane32_swap, then 5-stage half-reduce */           \
    swap32(c0, c4); float d0 = c0 + c4;                                       \
    swap32(c1, c5); float d1 = c1 + c5;                                       \
    swap32(c2, c6); float d2 = c2 + c6;                                       \
    swap32(c3, c7); float d3 = c3 + c7;                                       \
    d0 = half_reduce(d0); d1 = half_reduce(d1);                               \
    d2 = half_reduce(d2); d3 = half_reduce(d3);                               \
    x2[0][0] += __int_as_float(__builtin_amdgcn_readlane(__float_as_int(d0), laneA)); \
    x2[0][1] += __int_as_float(__builtin_amdgcn_readlane(__float_as_int(d1), laneA)); \
    x2[1][0] += __int_as_float(__builtin_amdgcn_readlane(__float_as_int(d2), laneA)); \
    x2[1][1] += __int_as_float(__builtin_amdgcn_readlane(__float_as_int(d3), laneA)); \
    x2[2][0] += __int_as_float(__builtin_amdgcn_readlane(__float_as_int(d0), laneB)); \
    x2[2][1] += __int_as_float(__builtin_amdgcn_readlane(__float_as_int(d1), laneB)); \
    x2[3][0] += __int_as_float(__builtin_amdgcn_readlane(__float_as_int(d2), laneB)); \
    x2[3][1] += __int_as_float(__builtin_amdgcn_readlane(__float_as_int(d3), laneB)); \
  }

  // prologue: groups 0 (A) and 1 (B)
  LOADG(Au, Ay);
  LOADG(Bu, By);

  // main: 255 double-group iterations (groups 0..509 processed,
  // loads reach group 511); epilogue handles groups 510, 511.
  for (int it = 0; it < 255; ++it) {
    STEP(Au[0], Ay[0]); STEP(Au[1], Ay[1]); STEP(Au[2], Ay[2]); STEP(Au[3], Ay[3]);
    LOADG(Au, Ay);
    STEP(Bu[0], By[0]); STEP(Bu[1], By[1]); STEP(Bu[2], By[2]); STEP(Bu[3], By[3]);
    LOADG(Bu, By);
  }
  STEP(Au[0], Ay[0]); STEP(Au[1], Ay[1]); STEP(Au[2], Ay[2]); STEP(Au[3], Ay[3]);
  STEP(Bu[0], By[0]); STEP(Bu[1], By[1]); STEP(Bu[2], By[2]); STEP(Bu[3], By[3]);
#undef STEP
#undef LOADG

  if (h == 0) {
#pragma unroll
    for (int p = 0; p < 4; ++p) {
      out[eb * NX + 2 * p]     = x2[p][0];
      out[eb * NX + 2 * p + 1] = x2[p][1];
    }
  }
}

extern "C" void kernel_launch(void* const* d_in, const int* in_sizes, int n_in,
                              void* d_out, int out_size, void* d_ws, size_t ws_size,
                              hipStream_t stream) {
  const float* u   = (const float*)d_in[0];
  const float* y   = (const float*)d_in[1];
  const float* Wf1 = (const float*)d_in[2];
  const float* bf1 = (const float*)d_in[3];
  const float* Wf2 = (const float*)d_in[4];
  const float* bf2 = (const float*)d_in[5];
  const float* Wg  = (const float*)d_in[6];
  const float* bg  = (const float*)d_in[7];
  const float* Wk1 = (const float*)d_in[8];
  const float* bk1 = (const float*)d_in[9];
  const float* Wk2 = (const float*)d_in[10];
  const float* bk2 = (const float*)d_in[11];

  luen_kernel<<<dim3(B_SZ), dim3(HID), 0, stream>>>(
      u, y, Wf1, bf1, Wf2, bf2, Wg, bg, Wk1, bk1, Wk2, bk2, (float*)d_out);
}

// Round 6
// 664.045 us; speedup vs baseline: 2.3117x; 1.0307x over previous
//
#include <hip/hip_runtime.h>

// Luenberger state estimator: T=2048 sequential steps, B=1024 independent
// elements. 1 wave/element (1024 blocks x 64 threads), lane h = hidden unit h
// of BOTH MLPs. R6 = proven R3 chassis + ONE new mechanism under test:
//  - VOP3P op_sel word-select splats on v_pk_fma_f32 in the c-block,
//    consuming packed hp={h1,h2} and ep={e0,e1} (kills 8 splat movs/step).
//  - Reduction is R3's PROVEN swap32 fold + 5-stage DPP half-reduce with
//    runtime direction probe. NO permlane16_swap (R5 post-mortem: broken/
//    mixing semantics on this HW). Canonical weight order (no kof).

#define T_STEPS 2048
#define B_SZ    1024
#define NX      8
#define HID     64

typedef float v2f __attribute__((ext_vector_type(2)));

// d = a*b + c
__device__ __forceinline__ v2f pk_fma(v2f a, v2f b, v2f c) {
  v2f d;
  asm("v_pk_fma_f32 %0, %1, %2, %3" : "=v"(d) : "v"(a), "v"(b), "v"(c));
  return d;
}
// acc += a*b
__device__ __forceinline__ void pk_fma_acc(v2f& acc, v2f a, v2f b) {
  asm("v_pk_fma_f32 %0, %1, %2, %0" : "+v"(acc) : "v"(a), "v"(b));
}
// d = splat_lo(a)*b + c   (a.lo feeds both halves)
__device__ __forceinline__ v2f pk_fma_s0lo(v2f a, v2f b, v2f c) {
  v2f d;
  asm("v_pk_fma_f32 %0, %1, %2, %3 op_sel:[0,0,0] op_sel_hi:[0,1,1]"
      : "=v"(d) : "v"(a), "v"(b), "v"(c));
  return d;
}
// d = splat_hi(a)*b + c   (a.hi feeds both halves)
__device__ __forceinline__ v2f pk_fma_s0hi(v2f a, v2f b, v2f c) {
  v2f d;
  asm("v_pk_fma_f32 %0, %1, %2, %3 op_sel:[1,0,0] op_sel_hi:[1,1,1]"
      : "=v"(d) : "v"(a), "v"(b), "v"(c));
  return d;
}
// acc += a*splat_lo(b)
__device__ __forceinline__ void pk_fma_acc_s1lo(v2f& acc, v2f a, v2f b) {
  asm("v_pk_fma_f32 %0, %1, %2, %0 op_sel:[0,0,0] op_sel_hi:[1,0,1]"
      : "+v"(acc) : "v"(a), "v"(b));
}
// acc += a*splat_hi(b)
__device__ __forceinline__ void pk_fma_acc_s1hi(v2f& acc, v2f a, v2f b) {
  asm("v_pk_fma_f32 %0, %1, %2, %0 op_sel:[0,1,0] op_sel_hi:[1,1,1]"
      : "+v"(acc) : "v"(a), "v"(b));
}

// tanh pair: inputs pre-scaled by 2*log2(e); returns {tanh(a), tanh(b)}
// packed in one v2f (plain C ops — compiler picks encodings; verified-safe).
__device__ __forceinline__ v2f tanh_pair(float pa, float pb) {
  v2f r;
  r[0] = __builtin_amdgcn_rcpf(__builtin_amdgcn_exp2f(pa) + 1.0f);
  r[1] = __builtin_amdgcn_rcpf(__builtin_amdgcn_exp2f(pb) + 1.0f);
  v2f h;
  h[0] = fmaf(-2.0f, r[0], 1.0f);
  h[1] = fmaf(-2.0f, r[1], 1.0f);
  return h;
}

template <int CTRL, int RMASK>
__device__ __forceinline__ float dpp_add(float acc) {
  int moved = __builtin_amdgcn_update_dpp(0, __float_as_int(acc), CTRL, RMASK, 0xf, true);
  return acc + __int_as_float(moved);
}

// after this, lane 31 = sum(lanes 0..31), lane 63 = sum(lanes 32..63)
__device__ __forceinline__ float half_reduce(float c) {
  c = dpp_add<0x111, 0xf>(c);  // row_shr:1
  c = dpp_add<0x112, 0xf>(c);  // row_shr:2
  c = dpp_add<0x114, 0xf>(c);  // row_shr:4
  c = dpp_add<0x118, 0xf>(c);  // row_shr:8
  c = dpp_add<0x142, 0xa>(c);  // row_bcast:15 into rows 1,3
  return c;
}

__device__ __forceinline__ void swap32(float& a, float& b) {
  asm("v_permlane32_swap_b32 %0, %1" : "+v"(a), "+v"(b));
}

__device__ __forceinline__ float rlf(float v, int lane) {
  return __int_as_float(__builtin_amdgcn_readlane(__float_as_int(v), lane));
}

__global__ __launch_bounds__(64, 1) void luen_kernel(
    const float* __restrict__ u, const float* __restrict__ y,
    const float* __restrict__ Wf1, const float* __restrict__ bf1,
    const float* __restrict__ Wf2, const float* __restrict__ bf2,
    const float* __restrict__ Wg, const float* __restrict__ bg,
    const float* __restrict__ Wk1, const float* __restrict__ bk1,
    const float* __restrict__ Wk2, const float* __restrict__ bk2,
    float* __restrict__ out) {
  const int eb = blockIdx.x;
  const int h  = threadIdx.x;

  const float TS = 2.885390081777927f;  // 2*log2(e)
  const float INV64 = 1.0f / 64.0f;

  // ---- per-lane weight columns (canonical order, as in R3) ----
  v2f wf1p[5];
#pragma unroll
  for (int p = 0; p < 5; ++p)
    wf1p[p] = v2f{TS * Wf1[(2 * p) * HID + h], TS * Wf1[(2 * p + 1) * HID + h]};
  v2f wk1p[4];
#pragma unroll
  for (int p = 0; p < 4; ++p)
    wk1p[p] = v2f{TS * Wk1[(2 * p) * HID + h], TS * Wk1[(2 * p + 1) * HID + h]};

  v2f wf2p[4], bf2sp[4];
#pragma unroll
  for (int p = 0; p < 4; ++p) {
    wf2p[p]  = v2f{Wf2[h * NX + 2 * p], Wf2[h * NX + 2 * p + 1]};
    bf2sp[p] = v2f{INV64 * bf2[2 * p], INV64 * bf2[2 * p + 1]};
  }
  v2f wk2e[4], wk2o[4], bk2se[4], bk2so[4];
#pragma unroll
  for (int p = 0; p < 4; ++p) {
    const float* r = Wk2 + h * (NX * 2);
    wk2e[p]  = v2f{r[4 * p], r[4 * p + 2]};
    wk2o[p]  = v2f{r[4 * p + 1], r[4 * p + 3]};
    bk2se[p] = v2f{INV64 * bk2[4 * p], INV64 * bk2[4 * p + 2]};
    bk2so[p] = v2f{INV64 * bk2[4 * p + 1], INV64 * bk2[4 * p + 3]};
  }
  v2f wgc0[4], wgc1[4];
#pragma unroll
  for (int p = 0; p < 4; ++p) {
    wgc0[p] = v2f{Wg[4 * p], Wg[4 * p + 2]};
    wgc1[p] = v2f{Wg[4 * p + 1], Wg[4 * p + 3]};
  }
  const v2f a0i = v2f{bg[0], 0.0f};
  const v2f a1i = v2f{bg[1], 0.0f};
  const v2f pfi = v2f{TS * bf1[h], 0.0f};
  const v2f pki = v2f{TS * bk1[h], 0.0f};

  // ---- permlane32_swap direction probe (one-time; exactly as R3) ----
  float probe = (h < 32) ? 0.0f : 1.0f;
  float zf = 0.0f;
  swap32(probe, zf);
  const bool dir1 = __builtin_amdgcn_readlane(__float_as_int(probe), 32) != 0;
  const int laneA = dir1 ? 63 : 31;  // sum of c[j]
  const int laneB = dir1 ? 31 : 63;  // sum of c[j+4]

  const v2f* __restrict__ pu = reinterpret_cast<const v2f*>(u) + eb;
  const v2f* __restrict__ py = reinterpret_cast<const v2f*>(y) + eb;
  const int STR = B_SZ;

  v2f x2[4];
#pragma unroll
  for (int p = 0; p < 4; ++p) x2[p] = v2f{0.0f, 0.0f};

  v2f Au[4], Ay[4], Bu[4], By[4];

#define LOADG(SET_u, SET_y)                          \
  {                                                  \
    SET_u[0] = pu[0 * STR]; SET_u[1] = pu[1 * STR];  \
    SET_u[2] = pu[2 * STR]; SET_u[3] = pu[3 * STR];  \
    SET_y[0] = py[0 * STR]; SET_y[1] = py[1 * STR];  \
    SET_y[2] = py[2 * STR]; SET_y[3] = py[3 * STR];  \
    pu += 4 * STR; py += 4 * STR;                    \
  }

#define STEP(CU_, CY_)                                                        \
  {                                                                           \
    const v2f cu = (CU_);                                                     \
    const v2f cy = (CY_);                                                     \
    /* y_hat and packed error ep = {e0, e1} */                                \
    v2f a0 = pk_fma(x2[0], wgc0[0], a0i);                                     \
    v2f a1 = pk_fma(x2[0], wgc1[0], a1i);                                     \
    pk_fma_acc(a0, x2[1], wgc0[1]); pk_fma_acc(a1, x2[1], wgc1[1]);           \
    pk_fma_acc(a0, x2[2], wgc0[2]); pk_fma_acc(a1, x2[2], wgc1[2]);           \
    pk_fma_acc(a0, x2[3], wgc0[3]); pk_fma_acc(a1, x2[3], wgc1[3]);           \
    v2f ep;                                                                   \
    ep[0] = a0[0] + a0[1] - cy[0];                                            \
    ep[1] = a1[0] + a1[1] - cy[1];                                            \
    /* f-net / k-net pre-activations -> packed hp = {h1, h2} */               \
    v2f pf = pk_fma(x2[0], wf1p[0], pfi);                                     \
    pk_fma_acc(pf, x2[1], wf1p[1]);                                           \
    pk_fma_acc(pf, x2[2], wf1p[2]);                                           \
    pk_fma_acc(pf, x2[3], wf1p[3]);                                           \
    pk_fma_acc(pf, cu, wf1p[4]);                                              \
    v2f pkv = pk_fma(x2[0], wk1p[0], pki);                                    \
    pk_fma_acc(pkv, x2[1], wk1p[1]);                                          \
    pk_fma_acc(pkv, x2[2], wk1p[2]);                                          \
    pk_fma_acc(pkv, x2[3], wk1p[3]);                                          \
    const v2f hp = tanh_pair(pf[0] + pf[1], pkv[0] + pkv[1]);                 \
    /* per-lane contributions: op_sel splats of hp / ep (UNDER TEST) */       \
    float c0, c1, c2, c3, c4, c5, c6, c7;                                     \
    {                                                                         \
      v2f t0 = pk_fma_s0hi(hp, wk2e[0], bk2se[0]);                            \
      v2f t1 = pk_fma_s0hi(hp, wk2o[0], bk2so[0]);                            \
      v2f cp = pk_fma_s0lo(hp, wf2p[0], bf2sp[0]);                            \
      pk_fma_acc_s1lo(cp, t0, ep);                                            \
      pk_fma_acc_s1hi(cp, t1, ep);                                            \
      c0 = cp[0]; c1 = cp[1];                                                 \
    }                                                                         \
    {                                                                         \
      v2f t0 = pk_fma_s0hi(hp, wk2e[1], bk2se[1]);                            \
      v2f t1 = pk_fma_s0hi(hp, wk2o[1], bk2so[1]);                            \
      v2f cp = pk_fma_s0lo(hp, wf2p[1], bf2sp[1]);                            \
      pk_fma_acc_s1lo(cp, t0, ep);                                            \
      pk_fma_acc_s1hi(cp, t1, ep);                                            \
      c2 = cp[0]; c3 = cp[1];                                                 \
    }                                                                         \
    {                                                                         \
      v2f t0 = pk_fma_s0hi(hp, wk2e[2], bk2se[2]);                            \
      v2f t1 = pk_fma_s0hi(hp, wk2o[2], bk2so[2]);                            \
      v2f cp = pk_fma_s0lo(hp, wf2p[2], bf2sp[2]);                            \
      pk_fma_acc_s1lo(cp, t0, ep);                                            \
      pk_fma_acc_s1hi(cp, t1, ep);                                            \
      c4 = cp[0]; c5 = cp[1];                                                 \
    }                                                                         \
    {                                                                         \
      v2f t0 = pk_fma_s0hi(hp, wk2e[3], bk2se[3]);                            \
      v2f t1 = pk_fma_s0hi(hp, wk2o[3], bk2so[3]);                            \
      v2f cp = pk_fma_s0lo(hp, wf2p[3], bf2sp[3]);                            \
      pk_fma_acc_s1lo(cp, t0, ep);                                            \
      pk_fma_acc_s1hi(cp, t1, ep);                                            \
      c6 = cp[0]; c7 = cp[1];                                                 \
    }                                                                         \
    /* PROVEN R3 reduction: swap32 fold + 5-stage half-reduce */              \
    swap32(c0, c4); float d0 = c0 + c4;                                       \
    swap32(c1, c5); float d1 = c1 + c5;                                       \
    swap32(c2, c6); float d2 = c2 + c6;                                       \
    swap32(c3, c7); float d3 = c3 + c7;                                       \
    d0 = half_reduce(d0); d1 = half_reduce(d1);                               \
    d2 = half_reduce(d2); d3 = half_reduce(d3);                               \
    x2[0][0] += rlf(d0, laneA);                                               \
    x2[0][1] += rlf(d1, laneA);                                               \
    x2[1][0] += rlf(d2, laneA);                                               \
    x2[1][1] += rlf(d3, laneA);                                               \
    x2[2][0] += rlf(d0, laneB);                                               \
    x2[2][1] += rlf(d1, laneB);                                               \
    x2[3][0] += rlf(d2, laneB);                                               \
    x2[3][1] += rlf(d3, laneB);                                               \
  }

  LOADG(Au, Ay);
  LOADG(Bu, By);

  for (int it = 0; it < 255; ++it) {
    STEP(Au[0], Ay[0]); STEP(Au[1], Ay[1]); STEP(Au[2], Ay[2]); STEP(Au[3], Ay[3]);
    LOADG(Au, Ay);
    STEP(Bu[0], By[0]); STEP(Bu[1], By[1]); STEP(Bu[2], By[2]); STEP(Bu[3], By[3]);
    LOADG(Bu, By);
  }
  STEP(Au[0], Ay[0]); STEP(Au[1], Ay[1]); STEP(Au[2], Ay[2]); STEP(Au[3], Ay[3]);
  STEP(Bu[0], By[0]); STEP(Bu[1], By[1]); STEP(Bu[2], By[2]); STEP(Bu[3], By[3]);
#undef STEP
#undef LOADG

  if (h == 0) {
#pragma unroll
    for (int p = 0; p < 4; ++p) {
      out[eb * NX + 2 * p]     = x2[p][0];
      out[eb * NX + 2 * p + 1] = x2[p][1];
    }
  }
}

extern "C" void kernel_launch(void* const* d_in, const int* in_sizes, int n_in,
                              void* d_out, int out_size, void* d_ws, size_t ws_size,
                              hipStream_t stream) {
  const float* u   = (const float*)d_in[0];
  const float* y   = (const float*)d_in[1];
  const float* Wf1 = (const float*)d_in[2];
  const float* bf1 = (const float*)d_in[3];
  const float* Wf2 = (const float*)d_in[4];
  const float* bf2 = (const float*)d_in[5];
  const float* Wg  = (const float*)d_in[6];
  const float* bg  = (const float*)d_in[7];
  const float* Wk1 = (const float*)d_in[8];
  const float* bk1 = (const float*)d_in[9];
  const float* Wk2 = (const float*)d_in[10];
  const float* bk2 = (const float*)d_in[11];

  luen_kernel<<<dim3(B_SZ), dim3(HID), 0, stream>>>(
      u, y, Wf1, bf1, Wf2, bf2, Wg, bg, Wk1, bk1, Wk2, bk2, (float*)d_out);
}